// Round 3
// baseline (110.944 us; speedup 1.0000x reference)
//
#include <hip/hip_runtime.h>

#define N 8192
#define Dk 128
#define EPSC 1e-6f
#define MARGIN 0.2f

typedef __attribute__((ext_vector_type(8))) short bf16x8;
typedef __attribute__((ext_vector_type(4))) float f32x4;

__device__ __forceinline__ unsigned short f2bf(float f) {
    unsigned u = __float_as_uint(f);
    u = (u + 0x7FFFu + ((u >> 16) & 1u)) >> 16;  // RNE fp32->bf16
    return (unsigned short)u;
}
// monotone float->uint encoding so atomicMax/Min on unsigned orders like float
__device__ __forceinline__ unsigned enc(float f) {
    unsigned u = __float_as_uint(f);
    return (u & 0x80000000u) ? ~u : (u | 0x80000000u);
}
__device__ __forceinline__ float dec(unsigned u) {
    return __uint_as_float((u & 0x80000000u) ? (u & 0x7FFFFFFFu) : ~u);
}

// Kernel A: bf16 copy of x, per-row P and QT (-Q/2, class), stat init. One wave per row.
__global__ void prep_kernel(const float* __restrict__ x, const int* __restrict__ tgt,
                            unsigned short* __restrict__ Xb, uint2* __restrict__ QT,
                            float* __restrict__ P,
                            unsigned* __restrict__ wsHp, unsigned* __restrict__ wsMn) {
    int row = blockIdx.x * 4 + (threadIdx.x >> 6);
    int l = threadIdx.x & 63;
    const float2 v = *reinterpret_cast<const float2*>(&x[row * Dk + l * 2]);
    float sq = fmaf(v.x, v.x, v.y * v.y);
    float s = v.x + v.y;
    ushort2 a;
    a.x = f2bf(v.x);
    a.y = f2bf(v.y);
    *reinterpret_cast<ushort2*>(&Xb[row * Dk + l * 2]) = a;
#pragma unroll
    for (int m = 32; m >= 1; m >>= 1) {
        sq += __shfl_xor(sq, m);
        s += __shfl_xor(s, m);
    }
    if (l == 0) {
        P[row] = sq - 2.0f * EPSC * s;
        float Qj = sq + 2.0f * EPSC * s + (float)Dk * EPSC * EPSC;
        uint2 qt;
        qt.x = __float_as_uint(-0.5f * Qj);
        qt.y = (unsigned)tgt[row];
        QT[row] = qt;
        wsHp[row] = 0xFF800000u;  // enc(+inf): identity for MIN (hardest_pos holds min acc)
        wsMn[row] = 0x007FFFFFu;  // enc(-inf): identity for MAX (hardest_neg holds max acc)
    }
}

// Kernel B: NO LDS, NO barriers. Block = 128 anchors x 1024 j (8 steps of 128).
// 4 waves, each 64i x 64j. A fragments persistent in registers; B fragments gathered
// straight from L2 (2 MB input is L2-resident). acc init = -Q_j/2, so after MFMA
// acc = dot - Q_j/2 and d2 = P_i - 2*acc (monotone DECREASING in acc):
//   hardest_pos = min acc over same-class; hardest_neg = max acc over diff-class.
__global__ __launch_bounds__(256, 2) void main_kernel(
        const unsigned short* __restrict__ Xb,
        const uint2* __restrict__ QT, const int* __restrict__ tgt,
        unsigned* __restrict__ wsHp, unsigned* __restrict__ wsMn) {
    const int tid = threadIdx.x;
    const int w = tid >> 6;
    const int lane = tid & 63;
    const int n = lane & 15;
    const int q = lane >> 4;
    const int wi = w >> 1;  // wave's i-half
    const int wj = w & 1;   // wave's j-half

    const int ig = (int)blockIdx.x >> 3;
    const int js = (int)blockIdx.x & 7;
    const int rbase = ig * 128 + 64 * wi;

    const bf16x8* Xv = reinterpret_cast<const bf16x8*>(Xb);  // row r chunk c -> Xv[r*16+c]

    // Persistent A fragments: 64 rows x K=128 per wave (64 VGPRs)
    bf16x8 Af[4][4];
#pragma unroll
    for (int ti = 0; ti < 4; ++ti)
#pragma unroll
        for (int kk = 0; kk < 4; ++kk)
            Af[ti][kk] = Xv[(rbase + 16 * ti + n) * 16 + (q + 4 * kk)];

    // anchor classes for this lane's 16 row-slots: row = rbase + 16*ti + 4*q + r
    int tsl[16];
#pragma unroll
    for (int ti = 0; ti < 4; ++ti) {
        int4 t4 = *reinterpret_cast<const int4*>(&tgt[rbase + 16 * ti + 4 * q]);
        tsl[4 * ti + 0] = t4.x;
        tsl[4 * ti + 1] = t4.y;
        tsl[4 * ti + 2] = t4.z;
        tsl[4 * ti + 3] = t4.w;
    }

    float hp[16], mn[16];
#pragma unroll
    for (int s = 0; s < 16; ++s) {
        hp[s] = INFINITY;   // min over same-class acc
        mn[s] = -INFINITY;  // max over diff-class acc
    }

    for (int step = 0; step < 8; ++step) {
        const int jbase = js * 1024 + step * 128;

        float Qv[4];
        int tv[4];
#pragma unroll
        for (int tj = 0; tj < 4; ++tj) {
            uint2 qt = QT[jbase + 64 * wj + 16 * tj + n];
            Qv[tj] = __uint_as_float(qt.x);  // = -Q_j/2
            tv[tj] = (int)qt.y;
        }

        f32x4 acc[4][4];
#pragma unroll
        for (int ti = 0; ti < 4; ++ti)
#pragma unroll
            for (int tj = 0; tj < 4; ++tj) acc[ti][tj] = Qv[tj];  // splat

#pragma unroll
        for (int kk = 0; kk < 4; ++kk) {
            bf16x8 Bf[4];
#pragma unroll
            for (int tj = 0; tj < 4; ++tj)
                Bf[tj] = Xv[(jbase + 64 * wj + 16 * tj + n) * 16 + (q + 4 * kk)];
#pragma unroll
            for (int ti = 0; ti < 4; ++ti)
#pragma unroll
                for (int tj = 0; tj < 4; ++tj)
                    acc[ti][tj] = __builtin_amdgcn_mfma_f32_16x16x32_bf16(Af[ti][kk], Bf[tj],
                                                                          acc[ti][tj], 0, 0, 0);
        }

        // Epilogue: acc elem r is (row rbase+16ti+4q+r, col jbase+64wj+16tj+n)
#pragma unroll
        for (int tj = 0; tj < 4; ++tj) {
            int tvv = tv[tj];
#pragma unroll
            for (int ti = 0; ti < 4; ++ti) {
                f32x4 v = acc[ti][tj];
                int e0 = tvv == tsl[4 * ti + 0];
                int e1 = tvv == tsl[4 * ti + 1];
                int e2 = tvv == tsl[4 * ti + 2];
                int e3 = tvv == tsl[4 * ti + 3];
                if (__ballot(e0 | e1 | e2 | e3)) {  // wave-uniform: tile has same-class pairs
                    hp[4 * ti + 0] = fminf(hp[4 * ti + 0], e0 ? v[0] : INFINITY);
                    hp[4 * ti + 1] = fminf(hp[4 * ti + 1], e1 ? v[1] : INFINITY);
                    hp[4 * ti + 2] = fminf(hp[4 * ti + 2], e2 ? v[2] : INFINITY);
                    hp[4 * ti + 3] = fminf(hp[4 * ti + 3], e3 ? v[3] : INFINITY);
                    mn[4 * ti + 0] = fmaxf(mn[4 * ti + 0], e0 ? -INFINITY : v[0]);
                    mn[4 * ti + 1] = fmaxf(mn[4 * ti + 1], e1 ? -INFINITY : v[1]);
                    mn[4 * ti + 2] = fmaxf(mn[4 * ti + 2], e2 ? -INFINITY : v[2]);
                    mn[4 * ti + 3] = fmaxf(mn[4 * ti + 3], e3 ? -INFINITY : v[3]);
                } else {  // fast path: all-negative tile
                    mn[4 * ti + 0] = fmaxf(mn[4 * ti + 0], v[0]);
                    mn[4 * ti + 1] = fmaxf(mn[4 * ti + 1], v[1]);
                    mn[4 * ti + 2] = fmaxf(mn[4 * ti + 2], v[2]);
                    mn[4 * ti + 3] = fmaxf(mn[4 * ti + 3], v[3]);
                }
            }
        }
    }

    // reduce across the 16 col-lanes; lane n==0 of each quad commits rows 4q+r
#pragma unroll
    for (int m = 1; m <= 8; m <<= 1) {
#pragma unroll
        for (int s = 0; s < 16; ++s) {
            hp[s] = fminf(hp[s], __shfl_xor(hp[s], m));
            mn[s] = fmaxf(mn[s], __shfl_xor(mn[s], m));
        }
    }
    if (n == 0) {
#pragma unroll
        for (int ti = 0; ti < 4; ++ti) {
#pragma unroll
            for (int r = 0; r < 4; ++r) {
                int i = rbase + 16 * ti + 4 * q + r;
                atomicMin(&wsHp[i], enc(hp[4 * ti + r]));
                atomicMax(&wsMn[i], enc(mn[4 * ti + r]));
            }
        }
    }
}

// Kernel C: single block, no atomics, writes out directly
__global__ void finish_kernel(const float* __restrict__ P,
                              const unsigned* __restrict__ wsHp,
                              const unsigned* __restrict__ wsMn,
                              float* __restrict__ out) {
    int t = threadIdx.x;  // 1024 threads
    float sum = 0.0f;
#pragma unroll
    for (int k = 0; k < 8; ++k) {
        int i = t + 1024 * k;
        float Pi = P[i];
        // d2 = P - 2*acc; hardest_pos from min-acc, hardest_neg from max-acc
        float hp = sqrtf(fmaxf(fmaf(-2.0f, dec(wsHp[i]), Pi), 0.0f));
        float hn = sqrtf(fmaxf(fmaf(-2.0f, dec(wsMn[i]), Pi), 0.0f));
        sum += fmaxf(hp - hn + MARGIN, 0.0f);
    }
#pragma unroll
    for (int m = 32; m >= 1; m >>= 1) sum += __shfl_xor(sum, m);
    __shared__ float ws[16];
    if ((t & 63) == 0) ws[t >> 6] = sum;
    __syncthreads();
    if (t == 0) {
        float tot = 0.0f;
#pragma unroll
        for (int i = 0; i < 16; ++i) tot += ws[i];
        out[0] = tot * (1.0f / (float)N);
    }
}

extern "C" void kernel_launch(void* const* d_in, const int* in_sizes, int n_in,
                              void* d_out, int out_size, void* d_ws, size_t ws_size,
                              hipStream_t stream) {
    const float* x = (const float*)d_in[0];
    const int* tgt = (const int*)d_in[1];
    float* out = (float*)d_out;

    char* ws = (char*)d_ws;
    const size_t xb = (size_t)N * Dk * 2;  // 2 MB bf16 copy
    unsigned short* Xb = (unsigned short*)ws;
    uint2* QT = (uint2*)(ws + xb);
    float* P = (float*)(ws + xb + (size_t)N * 8);
    unsigned* wsHp = (unsigned*)(ws + xb + (size_t)N * 12);
    unsigned* wsMn = (unsigned*)(ws + xb + (size_t)N * 16);

    prep_kernel<<<N / 4, 256, 0, stream>>>(x, tgt, Xb, QT, P, wsHp, wsMn);
    main_kernel<<<512, 256, 0, stream>>>(Xb, QT, tgt, wsHp, wsMn);
    finish_kernel<<<1, 1024, 0, stream>>>(P, wsHp, wsMn, out);
}

// Round 4
// 98.703 us; speedup vs baseline: 1.1240x; 1.1240x over previous
//
#include <hip/hip_runtime.h>

#define N 8192
#define Dk 128
#define EPSC 1e-6f
#define MARGIN 0.2f

typedef __attribute__((ext_vector_type(8))) short bf16x8;
typedef __attribute__((ext_vector_type(4))) float f32x4;

__device__ __forceinline__ unsigned short f2bf(float f) {
    unsigned u = __float_as_uint(f);
    u = (u + 0x7FFFu + ((u >> 16) & 1u)) >> 16;  // RNE fp32->bf16
    return (unsigned short)u;
}
// monotone float->uint encoding so atomicMax/Min on unsigned orders like float
__device__ __forceinline__ unsigned enc(float f) {
    unsigned u = __float_as_uint(f);
    return (u & 0x80000000u) ? ~u : (u | 0x80000000u);
}
__device__ __forceinline__ float dec(unsigned u) {
    return __uint_as_float((u & 0x80000000u) ? (u & 0x7FFFFFFFu) : ~u);
}

__device__ __forceinline__ void gl_lds16(const void* src, void* lds_dst) {
    __builtin_amdgcn_global_load_lds(
        (const __attribute__((address_space(1))) unsigned*)src,
        (__attribute__((address_space(3))) unsigned*)lds_dst, 16, 0, 0);
}

// Kernel A: SWIZZLED bf16 copy of x (16B chunk c of row r stored at chunk c^(r&7)),
// per-row P and QT (-Q/2, class), stat init. One wave per row.
__global__ void prep_kernel(const float* __restrict__ x, const int* __restrict__ tgt,
                            unsigned short* __restrict__ Xb, uint2* __restrict__ QT,
                            float* __restrict__ P,
                            unsigned* __restrict__ wsHp, unsigned* __restrict__ wsMn) {
    int row = blockIdx.x * 4 + (threadIdx.x >> 6);
    int l = threadIdx.x & 63;
    const float2 v = *reinterpret_cast<const float2*>(&x[row * Dk + l * 2]);
    float sq = fmaf(v.x, v.x, v.y * v.y);
    float s = v.x + v.y;
    ushort2 a;
    a.x = f2bf(v.x);
    a.y = f2bf(v.y);
    int c_phys = (l >> 2) ^ (row & 7);
    *reinterpret_cast<ushort2*>(&Xb[row * Dk + c_phys * 8 + 2 * (l & 3)]) = a;
#pragma unroll
    for (int m = 32; m >= 1; m >>= 1) {
        sq += __shfl_xor(sq, m);
        s += __shfl_xor(s, m);
    }
    if (l == 0) {
        P[row] = sq - 2.0f * EPSC * s;
        float Qj = sq + 2.0f * EPSC * s + (float)Dk * EPSC * EPSC;
        uint2 qt;
        qt.x = __float_as_uint(-0.5f * Qj);
        qt.y = (unsigned)tgt[row];
        QT[row] = qt;
        wsHp[row] = 0xFF800000u;  // enc(+inf): identity for MIN (hardest_pos = min acc)
        wsMn[row] = 0x007FFFFFu;  // enc(-inf): identity for MAX (hardest_neg = max acc)
    }
}

// Kernel B: block = 128 anchors x 1024 j (8 steps of 128), 4 waves of 64i x 64j.
// A persistent in registers. B double-buffered in LDS via async global_load_lds with a
// FULL-STEP prefetch distance: stage(step+1) issues right after the barrier, so the
// vmcnt(0) drain at the next barrier is already satisfied (no m97-style stall).
// acc init = -Q_j/2  =>  acc = dot - Q_j/2; d2 = P_i - 2*acc (monotone decreasing):
// hardest_pos = min acc over same-class, hardest_neg = max acc over diff-class.
__global__ __launch_bounds__(256, 2) void main_kernel(
        const unsigned short* __restrict__ Xb,
        const uint2* __restrict__ QT, const int* __restrict__ tgt,
        unsigned* __restrict__ wsHp, unsigned* __restrict__ wsMn) {
    __shared__ unsigned short Bs[2][128 * Dk];
    __shared__ uint2 QTs[2][128];

    const int tid = threadIdx.x;
    const int w = tid >> 6;
    const int lane = tid & 63;
    const int n = lane & 15;
    const int q = lane >> 4;
    const int wi = w >> 1;
    const int wj = w & 1;
    const int sw = n & 7;  // swizzle key: row&7 == n&7 for every row this lane touches

    const int ig = (int)blockIdx.x >> 3;
    const int js = (int)blockIdx.x & 7;
    const int rbase = ig * 128 + 64 * wi;

    const bf16x8* Xv = reinterpret_cast<const bf16x8*>(Xb);

    // Persistent A fragments: 64 rows x K=128 (64 VGPRs), gathered once from swizzled Xb
    bf16x8 Af[4][4];
#pragma unroll
    for (int ti = 0; ti < 4; ++ti)
#pragma unroll
        for (int kk = 0; kk < 4; ++kk)
            Af[ti][kk] = Xv[(rbase + 16 * ti + n) * 16 + ((q + 4 * kk) ^ sw)];

    int tsl[16];
#pragma unroll
    for (int ti = 0; ti < 4; ++ti) {
        int4 t4 = *reinterpret_cast<const int4*>(&tgt[rbase + 16 * ti + 4 * q]);
        tsl[4 * ti + 0] = t4.x;
        tsl[4 * ti + 1] = t4.y;
        tsl[4 * ti + 2] = t4.z;
        tsl[4 * ti + 3] = t4.w;
    }

    float hp[16], mn[16];
#pragma unroll
    for (int s = 0; s < 16; ++s) {
        hp[s] = INFINITY;
        mn[s] = -INFINITY;
    }

    // async stage of step's B tile (32 KB) + QT (1 KB) into buffer step&1
    auto stage = [&](int step) {
        const int jb = js * 1024 + step * 128;
        const int buf = step & 1;
#pragma unroll
        for (int t = 0; t < 8; ++t)
            gl_lds16(&Xb[(jb + 32 * w + 4 * t) * Dk] + lane * 8,
                     &Bs[buf][(32 * w + 4 * t) * Dk]);
        if (w == 0)
            gl_lds16(reinterpret_cast<const unsigned short*>(&QT[jb]) + lane * 8,
                     &QTs[buf][0]);
    };

    stage(0);

    for (int step = 0; step < 8; ++step) {
        const int buf = step & 1;
        __syncthreads();  // drain stage(step) (issued a full step ago => cheap) + buf reuse
        if (step < 7) stage(step + 1);  // async prefetch, consumed next step

        float Qv[4];
        int tv[4];
#pragma unroll
        for (int tj = 0; tj < 4; ++tj) {
            uint2 qt = QTs[buf][64 * wj + 16 * tj + n];
            Qv[tj] = __uint_as_float(qt.x);  // = -Q_j/2
            tv[tj] = (int)qt.y;
        }

        f32x4 acc[4][4];
#pragma unroll
        for (int ti = 0; ti < 4; ++ti)
#pragma unroll
            for (int tj = 0; tj < 4; ++tj) acc[ti][tj] = Qv[tj];

#pragma unroll
        for (int kk = 0; kk < 4; ++kk) {
            bf16x8 Bf[4];
#pragma unroll
            for (int tj = 0; tj < 4; ++tj)
                Bf[tj] = *reinterpret_cast<const bf16x8*>(
                    &Bs[buf][(64 * wj + 16 * tj + n) * Dk + (((q + 4 * kk) ^ sw) << 3)]);
#pragma unroll
            for (int ti = 0; ti < 4; ++ti)
#pragma unroll
                for (int tj = 0; tj < 4; ++tj)
                    acc[ti][tj] = __builtin_amdgcn_mfma_f32_16x16x32_bf16(Af[ti][kk], Bf[tj],
                                                                          acc[ti][tj], 0, 0, 0);
        }

        // Epilogue: acc elem r is (row rbase+16ti+4q+r, col jbase+64wj+16tj+n)
#pragma unroll
        for (int tj = 0; tj < 4; ++tj) {
            int tvv = tv[tj];
#pragma unroll
            for (int ti = 0; ti < 4; ++ti) {
                f32x4 v = acc[ti][tj];
                int e0 = tvv == tsl[4 * ti + 0];
                int e1 = tvv == tsl[4 * ti + 1];
                int e2 = tvv == tsl[4 * ti + 2];
                int e3 = tvv == tsl[4 * ti + 3];
                if (__ballot(e0 | e1 | e2 | e3)) {  // tile has same-class pairs (~23%)
                    hp[4 * ti + 0] = fminf(hp[4 * ti + 0], e0 ? v[0] : INFINITY);
                    hp[4 * ti + 1] = fminf(hp[4 * ti + 1], e1 ? v[1] : INFINITY);
                    hp[4 * ti + 2] = fminf(hp[4 * ti + 2], e2 ? v[2] : INFINITY);
                    hp[4 * ti + 3] = fminf(hp[4 * ti + 3], e3 ? v[3] : INFINITY);
                    mn[4 * ti + 0] = fmaxf(mn[4 * ti + 0], e0 ? -INFINITY : v[0]);
                    mn[4 * ti + 1] = fmaxf(mn[4 * ti + 1], e1 ? -INFINITY : v[1]);
                    mn[4 * ti + 2] = fmaxf(mn[4 * ti + 2], e2 ? -INFINITY : v[2]);
                    mn[4 * ti + 3] = fmaxf(mn[4 * ti + 3], e3 ? -INFINITY : v[3]);
                } else {  // all-negative tile fast path
                    mn[4 * ti + 0] = fmaxf(mn[4 * ti + 0], v[0]);
                    mn[4 * ti + 1] = fmaxf(mn[4 * ti + 1], v[1]);
                    mn[4 * ti + 2] = fmaxf(mn[4 * ti + 2], v[2]);
                    mn[4 * ti + 3] = fmaxf(mn[4 * ti + 3], v[3]);
                }
            }
        }
    }

    // reduce across the 16 col-lanes; lane n==0 of each quad commits rows 4q+r
#pragma unroll
    for (int m = 1; m <= 8; m <<= 1) {
#pragma unroll
        for (int s = 0; s < 16; ++s) {
            hp[s] = fminf(hp[s], __shfl_xor(hp[s], m));
            mn[s] = fmaxf(mn[s], __shfl_xor(mn[s], m));
        }
    }
    if (n == 0) {
#pragma unroll
        for (int ti = 0; ti < 4; ++ti) {
#pragma unroll
            for (int r = 0; r < 4; ++r) {
                int i = rbase + 16 * ti + 4 * q + r;
                atomicMin(&wsHp[i], enc(hp[4 * ti + r]));
                atomicMax(&wsMn[i], enc(mn[4 * ti + r]));
            }
        }
    }
}

// Kernel C: single block, vectorized loads, writes out directly
__global__ void finish_kernel(const float* __restrict__ P,
                              const unsigned* __restrict__ wsHp,
                              const unsigned* __restrict__ wsMn,
                              float* __restrict__ out) {
    int t = threadIdx.x;  // 1024 threads, thread t handles i in [8t, 8t+8)
    float sum = 0.0f;
#pragma unroll
    for (int h = 0; h < 2; ++h) {
        int base = 8 * t + 4 * h;
        float4 Pv = *reinterpret_cast<const float4*>(&P[base]);
        uint4 Hv = *reinterpret_cast<const uint4*>(&wsHp[base]);
        uint4 Mv = *reinterpret_cast<const uint4*>(&wsMn[base]);
        const float* Pf = &Pv.x;
        const unsigned* Hu = &Hv.x;
        const unsigned* Mu = &Mv.x;
#pragma unroll
        for (int k = 0; k < 4; ++k) {
            float hp = sqrtf(fmaxf(fmaf(-2.0f, dec(Hu[k]), Pf[k]), 0.0f));
            float hn = sqrtf(fmaxf(fmaf(-2.0f, dec(Mu[k]), Pf[k]), 0.0f));
            sum += fmaxf(hp - hn + MARGIN, 0.0f);
        }
    }
#pragma unroll
    for (int m = 32; m >= 1; m >>= 1) sum += __shfl_xor(sum, m);
    __shared__ float ws[16];
    if ((t & 63) == 0) ws[t >> 6] = sum;
    __syncthreads();
    if (t == 0) {
        float tot = 0.0f;
#pragma unroll
        for (int i = 0; i < 16; ++i) tot += ws[i];
        out[0] = tot * (1.0f / (float)N);
    }
}

extern "C" void kernel_launch(void* const* d_in, const int* in_sizes, int n_in,
                              void* d_out, int out_size, void* d_ws, size_t ws_size,
                              hipStream_t stream) {
    const float* x = (const float*)d_in[0];
    const int* tgt = (const int*)d_in[1];
    float* out = (float*)d_out;

    char* ws = (char*)d_ws;
    const size_t xb = (size_t)N * Dk * 2;  // 2 MB swizzled bf16 copy
    unsigned short* Xb = (unsigned short*)ws;
    uint2* QT = (uint2*)(ws + xb);
    float* P = (float*)(ws + xb + (size_t)N * 8);
    unsigned* wsHp = (unsigned*)(ws + xb + (size_t)N * 12);
    unsigned* wsMn = (unsigned*)(ws + xb + (size_t)N * 16);

    prep_kernel<<<N / 4, 256, 0, stream>>>(x, tgt, Xb, QT, P, wsHp, wsMn);
    main_kernel<<<512, 256, 0, stream>>>(Xb, QT, tgt, wsHp, wsMn);
    finish_kernel<<<1, 1024, 0, stream>>>(P, wsHp, wsMn, out);
}

// Round 5
// 97.003 us; speedup vs baseline: 1.1437x; 1.0175x over previous
//
#include <hip/hip_runtime.h>

#define N 8192
#define Dk 128
#define EPSC 1e-6f
#define MARGIN 0.2f

typedef __attribute__((ext_vector_type(8))) short bf16x8;
typedef __attribute__((ext_vector_type(4))) float f32x4;

__device__ __forceinline__ unsigned short f2bf(float f) {
    unsigned u = __float_as_uint(f);
    u = (u + 0x7FFFu + ((u >> 16) & 1u)) >> 16;  // RNE fp32->bf16
    return (unsigned short)u;
}
// monotone float->uint encoding so atomicMax/Min on unsigned orders like float
__device__ __forceinline__ unsigned enc(float f) {
    unsigned u = __float_as_uint(f);
    return (u & 0x80000000u) ? ~u : (u | 0x80000000u);
}
__device__ __forceinline__ float dec(unsigned u) {
    return __uint_as_float((u & 0x80000000u) ? (u & 0x7FFFFFFFu) : ~u);
}

__device__ __forceinline__ void gl_lds16(const void* src, void* lds_dst) {
    __builtin_amdgcn_global_load_lds(
        (const __attribute__((address_space(1))) unsigned*)src,
        (__attribute__((address_space(3))) unsigned*)lds_dst, 16, 0, 0);
}

// Kernel A: SWIZZLED bf16 copy of x (16B chunk c of row r stored at chunk c^(r&7)),
// per-row P and QT (-Q/2, class), stat init. One wave per row.
__global__ void prep_kernel(const float* __restrict__ x, const int* __restrict__ tgt,
                            unsigned short* __restrict__ Xb, uint2* __restrict__ QT,
                            float* __restrict__ P,
                            unsigned* __restrict__ wsHp, unsigned* __restrict__ wsMn) {
    int row = blockIdx.x * 4 + (threadIdx.x >> 6);
    int l = threadIdx.x & 63;
    const float2 v = *reinterpret_cast<const float2*>(&x[row * Dk + l * 2]);
    float sq = fmaf(v.x, v.x, v.y * v.y);
    float s = v.x + v.y;
    ushort2 a;
    a.x = f2bf(v.x);
    a.y = f2bf(v.y);
    int c_phys = (l >> 2) ^ (row & 7);
    *reinterpret_cast<ushort2*>(&Xb[row * Dk + c_phys * 8 + 2 * (l & 3)]) = a;
#pragma unroll
    for (int m = 32; m >= 1; m >>= 1) {
        sq += __shfl_xor(sq, m);
        s += __shfl_xor(s, m);
    }
    if (l == 0) {
        P[row] = sq - 2.0f * EPSC * s;
        float Qj = sq + 2.0f * EPSC * s + (float)Dk * EPSC * EPSC;
        uint2 qt;
        qt.x = __float_as_uint(-0.5f * Qj);
        qt.y = (unsigned)tgt[row];
        QT[row] = qt;
        wsHp[row] = 0xFF800000u;  // enc(+inf): identity for MIN (hardest_pos = min acc)
        wsMn[row] = 0x007FFFFFu;  // enc(-inf): identity for MAX (hardest_neg = max acc)
    }
}

// Kernel B: block = 128 anchors x 512 j (8 steps of 64), 4 waves stacked in i,
// each wave 32i x 64j per step. Af persistent in registers (32 VGPR). B + QT
// double-buffered in LDS via async global_load_lds, one-FULL-STEP prefetch distance.
// acc init = -Q_j/2 => acc = dot - Q_j/2; d2 = P_i - 2*acc (monotone decreasing):
// hardest_pos = min acc over same-class, hardest_neg = max acc over diff-class.
// __launch_bounds__(256,4): 4 waves/SIMD (<=128 regs), 4 blocks/CU (LDS 34 KB).
__global__ __launch_bounds__(256, 4) void main_kernel(
        const unsigned short* __restrict__ Xb,
        const uint2* __restrict__ QT, const int* __restrict__ tgt,
        unsigned* __restrict__ wsHp, unsigned* __restrict__ wsMn) {
    __shared__ unsigned short Bs[2][64 * Dk];  // 2 x 16 KB
    __shared__ uint2 QTs[2][128];              // 2 x 1 KB (upper 64 = staging slack)

    const int tid = threadIdx.x;
    const int w = tid >> 6;
    const int lane = tid & 63;
    const int n = lane & 15;
    const int q = lane >> 4;
    const int sw = n & 7;  // swizzle key: (global row)&7 == n&7 for rows this lane reads

    const int ig = (int)blockIdx.x >> 4;   // 0..63
    const int js = (int)blockIdx.x & 15;   // 0..15
    const int rbase = ig * 128 + 32 * w;   // this wave's 32 anchor rows

    const bf16x8* Xv = reinterpret_cast<const bf16x8*>(Xb);

    // Persistent A fragments: 32 rows x K=128 (32 VGPRs)
    bf16x8 Af[2][4];
#pragma unroll
    for (int ti = 0; ti < 2; ++ti)
#pragma unroll
        for (int kk = 0; kk < 4; ++kk)
            Af[ti][kk] = Xv[(rbase + 16 * ti + n) * 16 + ((q + 4 * kk) ^ sw)];

    // anchor classes for this lane's 8 row-slots: row = rbase + 16*ti + 4*q + r
    int tsl[8];
#pragma unroll
    for (int ti = 0; ti < 2; ++ti) {
        int4 t4 = *reinterpret_cast<const int4*>(&tgt[rbase + 16 * ti + 4 * q]);
        tsl[4 * ti + 0] = t4.x;
        tsl[4 * ti + 1] = t4.y;
        tsl[4 * ti + 2] = t4.z;
        tsl[4 * ti + 3] = t4.w;
    }

    float hp[8], mn[8];
#pragma unroll
    for (int s = 0; s < 8; ++s) {
        hp[s] = INFINITY;
        mn[s] = -INFINITY;
    }

    // async stage of step's B tile (16 KB) + QT (512 B used) into buffer step&1
    auto stage = [&](int step) {
        const int jb = js * 512 + step * 64;
        const int buf = step & 1;
#pragma unroll
        for (int t = 0; t < 4; ++t)  // wave w stages rows 16w+4t .. 16w+4t+3
            gl_lds16(&Xb[(jb + 16 * w + 4 * t) * Dk] + lane * 8,
                     &Bs[buf][(16 * w + 4 * t) * Dk]);
        if (w == 0)  // 1 KB instr covers QT[jb..jb+127]; upper half is staging slack
            gl_lds16(reinterpret_cast<const unsigned short*>(&QT[jb]) + lane * 8,
                     &QTs[buf][0]);
    };

    stage(0);

    for (int step = 0; step < 8; ++step) {
        const int buf = step & 1;
        __syncthreads();  // drains stage(step): issued a full step ago => cheap
        if (step < 7) stage(step + 1);  // async prefetch, consumed next step

        float Qv[4];
        int tv[4];
#pragma unroll
        for (int tj = 0; tj < 4; ++tj) {
            uint2 qt = QTs[buf][16 * tj + n];
            Qv[tj] = __uint_as_float(qt.x);  // = -Q_j/2
            tv[tj] = (int)qt.y;
        }

        f32x4 acc[2][4];
#pragma unroll
        for (int ti = 0; ti < 2; ++ti)
#pragma unroll
            for (int tj = 0; tj < 4; ++tj) acc[ti][tj] = Qv[tj];

#pragma unroll
        for (int kk = 0; kk < 4; ++kk) {
            bf16x8 Bf[4];
#pragma unroll
            for (int tj = 0; tj < 4; ++tj)
                Bf[tj] = *reinterpret_cast<const bf16x8*>(
                    &Bs[buf][(16 * tj + n) * Dk + (((q + 4 * kk) ^ sw) << 3)]);
#pragma unroll
            for (int ti = 0; ti < 2; ++ti)
#pragma unroll
                for (int tj = 0; tj < 4; ++tj)
                    acc[ti][tj] = __builtin_amdgcn_mfma_f32_16x16x32_bf16(Af[ti][kk], Bf[tj],
                                                                          acc[ti][tj], 0, 0, 0);
        }

        // Epilogue: acc elem r is (row rbase+16ti+4q+r, col jb+16tj+n)
#pragma unroll
        for (int tj = 0; tj < 4; ++tj) {
            int tvv = tv[tj];
#pragma unroll
            for (int ti = 0; ti < 2; ++ti) {
                f32x4 v = acc[ti][tj];
                int e0 = tvv == tsl[4 * ti + 0];
                int e1 = tvv == tsl[4 * ti + 1];
                int e2 = tvv == tsl[4 * ti + 2];
                int e3 = tvv == tsl[4 * ti + 3];
                if (__ballot(e0 | e1 | e2 | e3)) {  // tile has same-class pairs (~rare)
                    hp[4 * ti + 0] = fminf(hp[4 * ti + 0], e0 ? v[0] : INFINITY);
                    hp[4 * ti + 1] = fminf(hp[4 * ti + 1], e1 ? v[1] : INFINITY);
                    hp[4 * ti + 2] = fminf(hp[4 * ti + 2], e2 ? v[2] : INFINITY);
                    hp[4 * ti + 3] = fminf(hp[4 * ti + 3], e3 ? v[3] : INFINITY);
                    mn[4 * ti + 0] = fmaxf(mn[4 * ti + 0], e0 ? -INFINITY : v[0]);
                    mn[4 * ti + 1] = fmaxf(mn[4 * ti + 1], e1 ? -INFINITY : v[1]);
                    mn[4 * ti + 2] = fmaxf(mn[4 * ti + 2], e2 ? -INFINITY : v[2]);
                    mn[4 * ti + 3] = fmaxf(mn[4 * ti + 3], e3 ? -INFINITY : v[3]);
                } else {  // all-negative tile fast path
                    mn[4 * ti + 0] = fmaxf(mn[4 * ti + 0], v[0]);
                    mn[4 * ti + 1] = fmaxf(mn[4 * ti + 1], v[1]);
                    mn[4 * ti + 2] = fmaxf(mn[4 * ti + 2], v[2]);
                    mn[4 * ti + 3] = fmaxf(mn[4 * ti + 3], v[3]);
                }
            }
        }
    }

    // reduce across the 16 col-lanes; lane n==0 of each quad commits rows 4q+r
#pragma unroll
    for (int m = 1; m <= 8; m <<= 1) {
#pragma unroll
        for (int s = 0; s < 8; ++s) {
            hp[s] = fminf(hp[s], __shfl_xor(hp[s], m));
            mn[s] = fmaxf(mn[s], __shfl_xor(mn[s], m));
        }
    }
    if (n == 0) {
#pragma unroll
        for (int ti = 0; ti < 2; ++ti) {
#pragma unroll
            for (int r = 0; r < 4; ++r) {
                int i = rbase + 16 * ti + 4 * q + r;
                atomicMin(&wsHp[i], enc(hp[4 * ti + r]));
                atomicMax(&wsMn[i], enc(mn[4 * ti + r]));
            }
        }
    }
}

// Kernel C: single block, vectorized loads, writes out directly
__global__ void finish_kernel(const float* __restrict__ P,
                              const unsigned* __restrict__ wsHp,
                              const unsigned* __restrict__ wsMn,
                              float* __restrict__ out) {
    int t = threadIdx.x;  // 1024 threads, thread t handles i in [8t, 8t+8)
    float sum = 0.0f;
#pragma unroll
    for (int h = 0; h < 2; ++h) {
        int base = 8 * t + 4 * h;
        float4 Pv = *reinterpret_cast<const float4*>(&P[base]);
        uint4 Hv = *reinterpret_cast<const uint4*>(&wsHp[base]);
        uint4 Mv = *reinterpret_cast<const uint4*>(&wsMn[base]);
        const float* Pf = &Pv.x;
        const unsigned* Hu = &Hv.x;
        const unsigned* Mu = &Mv.x;
#pragma unroll
        for (int k = 0; k < 4; ++k) {
            float hp = sqrtf(fmaxf(fmaf(-2.0f, dec(Hu[k]), Pf[k]), 0.0f));
            float hn = sqrtf(fmaxf(fmaf(-2.0f, dec(Mu[k]), Pf[k]), 0.0f));
            sum += fmaxf(hp - hn + MARGIN, 0.0f);
        }
    }
#pragma unroll
    for (int m = 32; m >= 1; m >>= 1) sum += __shfl_xor(sum, m);
    __shared__ float ws[16];
    if ((t & 63) == 0) ws[t >> 6] = sum;
    __syncthreads();
    if (t == 0) {
        float tot = 0.0f;
#pragma unroll
        for (int i = 0; i < 16; ++i) tot += ws[i];
        out[0] = tot * (1.0f / (float)N);
    }
}

extern "C" void kernel_launch(void* const* d_in, const int* in_sizes, int n_in,
                              void* d_out, int out_size, void* d_ws, size_t ws_size,
                              hipStream_t stream) {
    const float* x = (const float*)d_in[0];
    const int* tgt = (const int*)d_in[1];
    float* out = (float*)d_out;

    char* ws = (char*)d_ws;
    const size_t xb = (size_t)N * Dk * 2;  // 2 MB swizzled bf16 copy
    unsigned short* Xb = (unsigned short*)ws;
    uint2* QT = (uint2*)(ws + xb);
    float* P = (float*)(ws + xb + (size_t)N * 8);
    unsigned* wsHp = (unsigned*)(ws + xb + (size_t)N * 12);
    unsigned* wsMn = (unsigned*)(ws + xb + (size_t)N * 16);

    prep_kernel<<<N / 4, 256, 0, stream>>>(x, tgt, Xb, QT, P, wsHp, wsMn);
    main_kernel<<<1024, 256, 0, stream>>>(Xb, QT, tgt, wsHp, wsMn);
    finish_kernel<<<1, 1024, 0, stream>>>(P, wsHp, wsMn, out);
}